// Round 13
// baseline (620.843 us; speedup 1.0000x reference)
//
#include <hip/hip_runtime.h>
#include <hip/hip_fp16.h>
#include <math.h>

#define N_NODES 40000
#define N_EDGES 640000
#define N_GRAPHS 32
#define HDIM 128
#define NHEADS 4
#define CDIM 32
#define NLAYERS 4
#define ODIM 100
#define SCAN_B 256
#define SCAN_NBLK ((N_NODES + SCAN_B - 1) / SCAN_B)   // 157
#define M_PAD 40064                                   // 313 * 128
#define POOL_CHUNK 32
#define POOL_NBLK ((N_NODES + POOL_CHUNK - 1) / POOL_CHUNK)  // 1250
#define SCALE 0.17677669529663687f                    // 1/sqrt(32)

typedef __bf16 bf16_t;
typedef bf16_t bf16x8 __attribute__((ext_vector_type(8)));
typedef float f32x4 __attribute__((ext_vector_type(4)));
typedef _Float16 h2v __attribute__((ext_vector_type(2)));

#if defined(__has_builtin)
#if __has_builtin(__builtin_amdgcn_fdot2)
#define HAVE_FDOT2 1
#endif
#endif

// packed k/v pair for one (channel, channel+16) pair of one node
struct __align__(8) H2P { __half2 k; __half2 v; };

// ---------------------------------------------------------------------------
// h = x @ node_w + node_b   ([N,4]@[4,128]) -> bf16 feature buffer
__global__ void nodeproj_kernel(const float* __restrict__ x,
                                const float* __restrict__ w,
                                const float* __restrict__ b,
                                bf16_t* __restrict__ hb) {
    int idx = blockIdx.x * blockDim.x + threadIdx.x;
    if (idx >= N_NODES * HDIM) return;
    int n = idx >> 7, c = idx & 127;
    float s = b[c];
    s += x[n * 4 + 0] * w[0 * HDIM + c];
    s += x[n * 4 + 1] * w[1 * HDIM + c];
    s += x[n * 4 + 2] * w[2 * HDIM + c];
    s += x[n * 4 + 3] * w[3 * HDIM + c];
    hb[idx] = (bf16_t)s;
}

// ---------------------------------------------------------------------------
// Me[i] = edge_w @ We[i]  ([5,128]),  ce[i] = edge_b @ We[i]  ([128])
__global__ void fold_edge_kernel(const float* __restrict__ edge_w,
                                 const float* __restrict__ edge_b,
                                 const float* __restrict__ We,
                                 float* __restrict__ Me_all,
                                 float* __restrict__ ce_all) {
    int blk = blockIdx.x;
    int i = blk / 6, j = blk % 6;
    int c = threadIdx.x;
    const float* W = We + (size_t)i * HDIM * HDIM;
    float s = 0.0f;
    if (j < 5) {
        for (int k = 0; k < HDIM; ++k) s += edge_w[j * HDIM + k] * W[k * HDIM + c];
        Me_all[i * 5 * HDIM + j * HDIM + c] = s;
    } else {
        for (int k = 0; k < HDIM; ++k) s += edge_b[k] * W[k * HDIM + c];
        ce_all[i * HDIM + c] = s;
    }
}

// ---------------------------------------------------------------------------
// CSR build
__global__ void count_deg_kernel(const int* __restrict__ ei, int* __restrict__ deg) {
    int e = blockIdx.x * blockDim.x + threadIdx.x;
    if (e >= N_EDGES) return;
    atomicAdd(&deg[ei[N_EDGES + e]], 1);
}

__global__ void scan1_kernel(const int* __restrict__ deg,
                             int* __restrict__ rowptr, int* __restrict__ bsum) {
    __shared__ int sd[SCAN_B];
    int tid = threadIdx.x;
    int i = blockIdx.x * SCAN_B + tid;
    int v = (i < N_NODES) ? deg[i] : 0;
    sd[tid] = v;
    __syncthreads();
#pragma unroll
    for (int off = 1; off < SCAN_B; off <<= 1) {
        int tmp = (tid >= off) ? sd[tid - off] : 0;
        __syncthreads();
        sd[tid] += tmp;
        __syncthreads();
    }
    if (i < N_NODES) rowptr[i] = sd[tid] - v;
    if (tid == SCAN_B - 1) bsum[blockIdx.x] = sd[tid];
}

__global__ void scan2_kernel(const int* __restrict__ bsum, int* __restrict__ bscan) {
    __shared__ int sd[SCAN_B];
    int tid = threadIdx.x;
    int v = (tid < SCAN_NBLK) ? bsum[tid] : 0;
    sd[tid] = v;
    __syncthreads();
#pragma unroll
    for (int off = 1; off < SCAN_B; off <<= 1) {
        int tmp = (tid >= off) ? sd[tid - off] : 0;
        __syncthreads();
        sd[tid] += tmp;
        __syncthreads();
    }
    if (tid < SCAN_NBLK) bscan[tid] = sd[tid] - v;
}

__global__ void scan3_kernel(int* __restrict__ rowptr, const int* __restrict__ bscan) {
    int i = blockIdx.x * SCAN_B + threadIdx.x;
    if (i < N_NODES) rowptr[i] += bscan[blockIdx.x];
    if (i == 0) rowptr[N_NODES] = N_EDGES;
}

// scatter src + edge attrs (padded to 8 floats -> two float4 stores)
__global__ void fill_csr_kernel(const int* __restrict__ ei,
                                const float* __restrict__ ea,
                                const int* __restrict__ rowptr,
                                int* __restrict__ cursor,
                                int* __restrict__ srcarr,
                                float* __restrict__ ea8) {
    int e = blockIdx.x * blockDim.x + threadIdx.x;
    if (e >= N_EDGES) return;
    int src = ei[e], dst = ei[N_EDGES + e];
    int pos = atomicAdd(&cursor[dst], 1);
    int p = rowptr[dst] + pos;
    srcarr[p] = src;
    float4 lo = make_float4(ea[(size_t)e * 5 + 0], ea[(size_t)e * 5 + 1],
                            ea[(size_t)e * 5 + 2], ea[(size_t)e * 5 + 3]);
    float4 hi = make_float4(ea[(size_t)e * 5 + 4], 0.f, 0.f, 0.f);
    *(float4*)(ea8 + (size_t)p * 8)     = lo;
    *(float4*)(ea8 + (size_t)p * 8 + 4) = hi;
}

// ---------------------------------------------------------------------------
// Convert weights to bf16 [n][k]; Wk pre-scaled by 1/sqrt(C).
__global__ void convert_w_kernel(const float* __restrict__ Wq, const float* __restrict__ Wk,
                                 const float* __restrict__ Wv, const float* __restrict__ Ws,
                                 bf16_t* __restrict__ Wtb) {
    int b = blockIdx.x;
    int n = b & 127;
    int matli = b >> 7;
    int mat = matli & 3, li = matli >> 2;
    int kk = threadIdx.x;
    const float* W = (mat == 0 ? Wq : mat == 1 ? Wk : mat == 2 ? Wv : Ws) + (size_t)li * HDIM * HDIM;
    float val = W[kk * HDIM + n];
    if (mat == 1) val *= SCALE;
    Wtb[((size_t)(li * 4 + mat) * HDIM + n) * HDIM + kk] = (bf16_t)val;
}

// ---------------------------------------------------------------------------
// Fused projection GEMM (round-6 known-good). blockIdx.y: 0 -> q (packed
// half2 pairs), 1 -> k&v (H2P pairs, k pre-scaled), 2 -> skip (fp32).
// NOTE (r7 post-mortem): register-direct B from global regressed -- keep
// LDS-staged B.
__global__ __launch_bounds__(256) void gemm_mfma(
    const bf16_t* __restrict__ hb, const bf16_t* __restrict__ Wt,
    const float* __restrict__ bq, const float* __restrict__ bk,
    const float* __restrict__ bv, const float* __restrict__ bs,
    __half2* __restrict__ q2o, H2P* __restrict__ kv2o,
    float* __restrict__ so) {
    __shared__ bf16_t Ash[128 * 128];
    __shared__ bf16_t Bsh[128 * 128];
    int tid = threadIdx.x;
    int mt = blockIdx.y;
    int row0 = blockIdx.x * 128;
    int r = tid >> 4, g = tid & 15;

    {   // stage A and first B (q: slot0, kv: slot1=k, skip: slot3)
        const bf16_t* W0 = Wt + (size_t)(mt == 0 ? 0 : (mt == 1 ? 1 : 3)) * HDIM * HDIM;
#pragma unroll
        for (int p = 0; p < 8; ++p) {
            int rr = p * 16 + r;
            int sw = (g ^ (rr & 15)) << 3;
            *(bf16x8*)(Ash + rr * 128 + sw) = *(const bf16x8*)(hb + (size_t)(row0 + rr) * HDIM + g * 8);
            *(bf16x8*)(Bsh + rr * 128 + sw) = *(const bf16x8*)(W0 + (size_t)rr * HDIM + g * 8);
        }
    }
    __syncthreads();

    int lane = tid & 63, wave = tid >> 6;
    int wr = (wave >> 1) * 64, wc = (wave & 1) * 64;
    int lm = lane & 15, quad = lane >> 4;

    f32x4 acc[4][4];
#pragma unroll
    for (int i = 0; i < 4; ++i)
#pragma unroll
        for (int j = 0; j < 4; ++j) acc[i][j] = (f32x4){0.f, 0.f, 0.f, 0.f};

#pragma unroll
    for (int ks = 0; ks < 4; ++ks) {
        int gg = ks * 4 + quad;
        int sw = (gg ^ lm) << 3;
        bf16x8 af[4], bf[4];
#pragma unroll
        for (int t = 0; t < 4; ++t) {
            af[t] = *(const bf16x8*)(Ash + (wr + t * 16 + lm) * 128 + sw);
            bf[t] = *(const bf16x8*)(Bsh + (wc + t * 16 + lm) * 128 + sw);
        }
#pragma unroll
        for (int i = 0; i < 4; ++i)
#pragma unroll
            for (int j = 0; j < 4; ++j)
                acc[i][j] = __builtin_amdgcn_mfma_f32_16x16x32_bf16(af[i], bf[j], acc[i][j], 0, 0, 0);
    }

    int c0 = wc + lm;           // low channel of pair (j0,j1)
    int c2 = wc + lm + 32;      // low channel of pair (j2,j3)
    int pi0 = ((c0 >> 5) << 4) | lm;
    int pi1 = ((c2 >> 5) << 4) | lm;

    if (mt == 0) {
        float b0 = bq[c0], b1 = bq[c0 + 16], b2 = bq[c2], b3 = bq[c2 + 16];
#pragma unroll
        for (int i = 0; i < 4; ++i) {
            int rbase = row0 + wr + i * 16 + quad * 4;
#pragma unroll
            for (int rr2 = 0; rr2 < 4; ++rr2) {
                int row = rbase + rr2;
                if (row < N_NODES) {
                    q2o[(size_t)row * 64 + pi0] =
                        __floats2half2_rn(acc[i][0][rr2] + b0, acc[i][1][rr2] + b1);
                    q2o[(size_t)row * 64 + pi1] =
                        __floats2half2_rn(acc[i][2][rr2] + b2, acc[i][3][rr2] + b3);
                }
            }
        }
    } else if (mt == 1) {
        // second pass: v (slot 2)
        f32x4 acc2[4][4];
#pragma unroll
        for (int i = 0; i < 4; ++i)
#pragma unroll
            for (int j = 0; j < 4; ++j) acc2[i][j] = (f32x4){0.f, 0.f, 0.f, 0.f};
        __syncthreads();
        {
            const bf16_t* W1 = Wt + (size_t)2 * HDIM * HDIM;
#pragma unroll
            for (int p = 0; p < 8; ++p) {
                int rr = p * 16 + r;
                int sw = (g ^ (rr & 15)) << 3;
                *(bf16x8*)(Bsh + rr * 128 + sw) = *(const bf16x8*)(W1 + (size_t)rr * HDIM + g * 8);
            }
        }
        __syncthreads();
#pragma unroll
        for (int ks = 0; ks < 4; ++ks) {
            int gg = ks * 4 + quad;
            int sw = (gg ^ lm) << 3;
            bf16x8 af[4], bf[4];
#pragma unroll
            for (int t = 0; t < 4; ++t) {
                af[t] = *(const bf16x8*)(Ash + (wr + t * 16 + lm) * 128 + sw);
                bf[t] = *(const bf16x8*)(Bsh + (wc + t * 16 + lm) * 128 + sw);
            }
#pragma unroll
            for (int i = 0; i < 4; ++i)
#pragma unroll
                for (int j = 0; j < 4; ++j)
                    acc2[i][j] = __builtin_amdgcn_mfma_f32_16x16x32_bf16(af[i], bf[j], acc2[i][j], 0, 0, 0);
        }
        float kb0 = bk[c0] * SCALE, kb1 = bk[c0 + 16] * SCALE;
        float kb2 = bk[c2] * SCALE, kb3 = bk[c2 + 16] * SCALE;
        float vb0 = bv[c0], vb1 = bv[c0 + 16], vb2 = bv[c2], vb3 = bv[c2 + 16];
#pragma unroll
        for (int i = 0; i < 4; ++i) {
            int rbase = row0 + wr + i * 16 + quad * 4;
#pragma unroll
            for (int rr2 = 0; rr2 < 4; ++rr2) {
                int row = rbase + rr2;
                if (row < N_NODES) {
                    H2P h0, h1;
                    h0.k = __floats2half2_rn(acc[i][0][rr2] + kb0, acc[i][1][rr2] + kb1);
                    h0.v = __floats2half2_rn(acc2[i][0][rr2] + vb0, acc2[i][1][rr2] + vb1);
                    h1.k = __floats2half2_rn(acc[i][2][rr2] + kb2, acc[i][3][rr2] + kb3);
                    h1.v = __floats2half2_rn(acc2[i][2][rr2] + vb2, acc2[i][3][rr2] + vb3);
                    kv2o[(size_t)row * 64 + pi0] = h0;
                    kv2o[(size_t)row * 64 + pi1] = h1;
                }
            }
        }
    } else {
#pragma unroll
        for (int i = 0; i < 4; ++i) {
            int rbase = row0 + wr + i * 16 + quad * 4;
#pragma unroll
            for (int j = 0; j < 4; ++j) {
                int col = wc + j * 16 + lm;
                float bcol = bs[col];
#pragma unroll
                for (int rr2 = 0; rr2 < 4; ++rr2) {
                    int row = rbase + rr2;
                    if (row < N_NODES) so[(size_t)row * HDIM + col] = acc[i][j][rr2] + bcol;
                }
            }
        }
    }
}

// ---------------------------------------------------------------------------
// Fused per-dst-node attention + skip + LayerNorm + ReLU.
// ONE WAVE per node; lane t owns channel pair (clo, clo+16). No online max
// (r9). r10: two-deep pipeline. r12: 2x-unrolled PING-PONG pipeline -- kv/src
// buffers overwritten in place (rotation was ~5 mov/edge, now ~1); group count
// rounded up to even, phantom groups masked via clamped indices + pe=0.
// Score k-dot via v_dot2_f32_f16 (fp32 accumulate -- numerically identical).
__global__ __launch_bounds__(128) void agg_kernel(
    const int* __restrict__ srcarr, const int* __restrict__ rowptr,
    const float* __restrict__ ea8,
    const __half2* __restrict__ q2,
    const H2P* __restrict__ kv2,
    const float* __restrict__ Me, const float* __restrict__ ce,
    const float* __restrict__ skip,
    const float* __restrict__ lg, const float* __restrict__ lb,
    bf16_t* __restrict__ hbout) {
    int t = threadIdx.x & 63;
    int n = blockIdx.x * 2 + (threadIdx.x >> 6);
    int cc = t & 15;
    int clo = ((t >> 4) << 5) | cc;
    int chi = clo + 16;

    __half2 qh = q2[(size_t)n * 64 + t];
    float2 qf = __half22float2(qh);
    float cwlo = ce[clo], cwhi = ce[chi];
    float mlo[5], mhi[5];
#pragma unroll
    for (int j = 0; j < 5; ++j) { mlo[j] = Me[j * HDIM + clo]; mhi[j] = Me[j * HDIM + chi]; }

    // per-node per-head preamble: lane cc==j gets SCALE * (q_h . Mvec_j_h)
    float myq = 0.0f;
#pragma unroll
    for (int j = 0; j < 6; ++j) {
        float a = (j < 5) ? mlo[j] : cwlo;
        float b = (j < 5) ? mhi[j] : cwhi;
        float p = (qf.x * a + qf.y * b) * SCALE;
        p += __shfl_xor(p, 8, 16);
        p += __shfl_xor(p, 4, 16);
        p += __shfl_xor(p, 2, 16);
        p += __shfl_xor(p, 1, 16);
        if (cc == j) myq = p;
    }

    int beg = rowptr[n], end = rowptr[n + 1];
    float l[4], o0[4], o1[4], ab[4];
#pragma unroll
    for (int s = 0; s < 4; ++s) { l[s] = 0.f; o0[s] = 0.f; o1[s] = 0.f; ab[s] = 0.f; }

    if (beg < end) {   // wave-uniform; deg-0 nodes skip all loads
        int e1 = end - 1;

        auto loadIdx = [&](int base, int* src, float* av) {
#pragma unroll
            for (int s = 0; s < 4; ++s) {
                int ci = base + s; ci = (ci < e1) ? ci : e1;
                src[s] = srcarr[ci];
                av[s] = (cc < 5) ? ea8[(size_t)ci * 8 + cc] : 1.0f;
            }
        };
        auto loadKv = [&](const int* src, H2P* kv) {
#pragma unroll
            for (int s = 0; s < 4; ++s) kv[s] = kv2[(size_t)src[s] * 64 + t];
        };
        auto process = [&](int base, const H2P* kv, const float* av) {
            float p4[4], vx[4], vy[4];
#pragma unroll
            for (int s = 0; s < 4; ++s) {
                float2 vf = __half22float2(kv[s].v);
                vx[s] = vf.x; vy[s] = vf.y;
                float pa = myq * av[s];
#if defined(HAVE_FDOT2)
                p4[s] = __builtin_amdgcn_fdot2(__builtin_bit_cast(h2v, qh),
                                               __builtin_bit_cast(h2v, kv[s].k), pa, false);
#else
                float2 kf = __half22float2(kv[s].k);
                p4[s] = fmaf(qf.x, kf.x, fmaf(qf.y, kf.y, pa));
#endif
            }
#pragma unroll
            for (int st = 8; st >= 1; st >>= 1) {
#pragma unroll
                for (int s = 0; s < 4; ++s) p4[s] += __shfl_xor(p4[s], st, 16);
            }
#pragma unroll
            for (int s = 0; s < 4; ++s) {
                float pe = (base + s < end) ? __expf(p4[s]) : 0.0f;  // phantom -> 0
                o0[s] = fmaf(pe, vx[s], o0[s]);
                o1[s] = fmaf(pe, vy[s], o1[s]);
                l[s] += pe;
                ab[s] = fmaf(pe, av[s], ab[s]);
            }
        };

        int ng = (end - beg + 3) >> 2;       // groups of 4 edges
        int npairs = (ng + 1) >> 1;          // process 2 groups/iter (phantom-safe)

        int srcA[4], srcB[4];
        float avA[4], avB[4], avC[4], avD[4];
        H2P kvA[4], kvB[4];

        loadIdx(beg, srcA, avA);
        loadIdx(beg + 4, srcB, avB);
        loadKv(srcA, kvA);

        int base = beg;
        for (int p = 0; p < npairs; ++p) {
            loadKv(srcB, kvB);               // kv for G+1
            loadIdx(base + 8, srcA, avC);    // idx for G+2 (srcA free)
            process(base, kvA, avA);         // G
            loadKv(srcA, kvA);               // kv for G+2 (in-place, no movs)
            loadIdx(base + 12, srcB, avD);   // idx for G+3 (srcB free)
            process(base + 4, kvB, avB);     // G+1
#pragma unroll
            for (int s = 0; s < 4; ++s) { avA[s] = avC[s]; avB[s] = avD[s]; }
            base += 8;
        }
    }
    // merge 4 states: plain sums
    float lt  = (l[0] + l[1]) + (l[2] + l[3]);
    float o0t = (o0[0] + o0[1]) + (o0[2] + o0[3]);
    float o1t = (o1[0] + o1[1]) + (o1[2] + o1[3]);
    float abt = (ab[0] + ab[1]) + (ab[2] + ab[3]);

    // msg = (o + l*ce + sum_j Me_j * ab_j) / (l + 1e-16)
    float nlo = fmaf(lt, cwlo, o0t);
    float nhi = fmaf(lt, cwhi, o1t);
#pragma unroll
    for (int j = 0; j < 5; ++j) {
        float abj = __shfl(abt, (t & 48) + j, 64);
        nlo = fmaf(mlo[j], abj, nlo);
        nhi = fmaf(mhi[j], abj, nhi);
    }
    float inv = 1.0f / (lt + 1e-16f);
    float vlo = skip[(size_t)n * HDIM + clo] + nlo * inv;
    float vhi = skip[(size_t)n * HDIM + chi] + nhi * inv;

    // LayerNorm over 128 channels -- single-wave butterfly
    float s = vlo + vhi;
#pragma unroll
    for (int mask = 32; mask >= 1; mask >>= 1) s += __shfl_xor(s, mask, 64);
    float mu = s * (1.0f / HDIM);
    float dlo = vlo - mu, dhi = vhi - mu;
    float s2 = dlo * dlo + dhi * dhi;
#pragma unroll
    for (int mask = 32; mask >= 1; mask >>= 1) s2 += __shfl_xor(s2, mask, 64);
    float rstd = rsqrtf(s2 * (1.0f / HDIM) + 1e-5f);
    float ylo = fmaxf(dlo * rstd * lg[clo] + lb[clo], 0.0f);
    float yhi = fmaxf(dhi * rstd * lg[chi] + lb[chi], 0.0f);
    hbout[(size_t)n * HDIM + clo] = (bf16_t)ylo;
    hbout[(size_t)n * HDIM + chi] = (bf16_t)yhi;
}

// ---------------------------------------------------------------------------
// Chunked mean-pool. r11: POOL_CHUNK 256->32 (157->1250 blocks).
__global__ __launch_bounds__(128) void pool_kernel(const bf16_t* __restrict__ h,
                                                   const int* __restrict__ batch,
                                                   float* __restrict__ pool,
                                                   float* __restrict__ cnt) {
    int t = threadIdx.x;
    int n0 = blockIdx.x * POOL_CHUNK;
    int n1 = n0 + POOL_CHUNK;
    if (n1 > N_NODES) n1 = N_NODES;
    int gcur = batch[n0];
    int cstart = n0;
    float acc = 0.0f;
    for (int n = n0; n < n1; ++n) {
        int g = batch[n];
        if (g != gcur) {
            atomicAdd(&pool[gcur * HDIM + t], acc);
            if (t == 0) atomicAdd(&cnt[gcur], (float)(n - cstart));
            acc = 0.0f;
            gcur = g;
            cstart = n;
        }
        acc += (float)h[(size_t)n * HDIM + t];
    }
    atomicAdd(&pool[gcur * HDIM + t], acc);
    if (t == 0) atomicAdd(&cnt[gcur], (float)(n1 - cstart));
}

// ---------------------------------------------------------------------------
__global__ void heads_kernel(const float* __restrict__ pool,
                             const float* __restrict__ cnt,
                             const float* __restrict__ dw1, const float* __restrict__ db1,
                             const float* __restrict__ dw2, const float* __restrict__ db2,
                             const float* __restrict__ tw1, const float* __restrict__ tb1,
                             const float* __restrict__ tw2, const float* __restrict__ tb2,
                             float* __restrict__ outp) {
    int g = blockIdx.x, t = threadIdx.x;
    __shared__ float hg[HDIM];
    __shared__ float hid[64];
    float c = fmaxf(cnt[g], 1.0f);
    hg[t] = pool[g * HDIM + t] / c;
    __syncthreads();
    if (t < 64) {
        float s = db1[t];
        for (int i = 0; i < HDIM; ++i) s += hg[i] * dw1[i * 64 + t];
        hid[t] = fmaxf(s, 0.0f);
    }
    __syncthreads();
    if (t < ODIM) {
        float s = db2[t];
        for (int j = 0; j < 64; ++j) s += hid[j] * dw2[j * ODIM + t];
        outp[g * ODIM + t] = s;
    }
    __syncthreads();
    if (t < 64) {
        float s = tb1[t];
        for (int i = 0; i < HDIM; ++i) s += hg[i] * tw1[i * 64 + t];
        hid[t] = fmaxf(s, 0.0f);
    }
    __syncthreads();
    if (t < ODIM) {
        float s = tb2[t];
        for (int j = 0; j < 64; ++j) s += hid[j] * tw2[j * ODIM + t];
        outp[N_GRAPHS * ODIM + g * ODIM + t] = s;
    }
}

// ---------------------------------------------------------------------------
extern "C" void kernel_launch(void* const* d_in, const int* in_sizes, int n_in,
                              void* d_out, int out_size, void* d_ws, size_t ws_size,
                              hipStream_t stream) {
    const float* x        = (const float*)d_in[0];
    const float* ea       = (const float*)d_in[1];
    const float* node_w   = (const float*)d_in[2];
    const float* node_b   = (const float*)d_in[3];
    const float* edge_w   = (const float*)d_in[4];
    const float* edge_b   = (const float*)d_in[5];
    const float* Wq       = (const float*)d_in[6];
    const float* bq       = (const float*)d_in[7];
    const float* Wk       = (const float*)d_in[8];
    const float* bk       = (const float*)d_in[9];
    const float* Wv       = (const float*)d_in[10];
    const float* bv       = (const float*)d_in[11];
    const float* We       = (const float*)d_in[12];
    const float* Wskip    = (const float*)d_in[13];
    const float* bskip    = (const float*)d_in[14];
    const float* ln_g     = (const float*)d_in[15];
    const float* ln_b     = (const float*)d_in[16];
    const float* dw1      = (const float*)d_in[17];
    const float* db1      = (const float*)d_in[18];
    const float* dw2      = (const float*)d_in[19];
    const float* db2      = (const float*)d_in[20];
    const float* tw1      = (const float*)d_in[21];
    const float* tb1      = (const float*)d_in[22];
    const float* tw2      = (const float*)d_in[23];
    const float* tb2      = (const float*)d_in[24];
    const int*   ei       = (const int*)d_in[25];
    const int*   batch    = (const int*)d_in[26];
    float* out = (float*)d_out;
    (void)in_sizes; (void)n_in; (void)out_size; (void)ws_size;

    // ---- workspace carve (256B aligned) ----
    char* wsb = (char*)d_ws;
    size_t off = 0;
    auto carve = [&](size_t bytes) -> void* {
        void* p = wsb + off;
        off += (bytes + 255) & ~(size_t)255;
        return p;
    };
    bf16_t*  hbuf   = (bf16_t*) carve((size_t)M_PAD * HDIM * 2);
    __half2* q2b    = (__half2*)carve((size_t)N_NODES * 64 * 4);
    H2P*     kv2b   = (H2P*)    carve((size_t)N_NODES * 64 * 8);
    float*   ob     = (float*)  carve((size_t)N_NODES * HDIM * 4);   // skip buffer
    bf16_t*  Wtb    = (bf16_t*) carve((size_t)NLAYERS * 4 * HDIM * HDIM * 2);
    int*     srcarr = (int*)    carve((size_t)N_EDGES * 4);
    float*   ea8    = (float*)  carve((size_t)N_EDGES * 8 * 4);
    int*     deg    = (int*)    carve((size_t)N_NODES * 4);          // 160000 B (256-mult)
    int*     cursor = (int*)    carve((size_t)N_NODES * 4);          // adjacent to deg
    int*     rowptr = (int*)    carve((size_t)(N_NODES + 1) * 4);
    int*     bsum   = (int*)    carve((size_t)SCAN_NBLK * 4);
    int*     bscan  = (int*)    carve((size_t)SCAN_NBLK * 4);
    float*   Me_all = (float*)  carve((size_t)NLAYERS * 5 * HDIM * 4);
    float*   ce_all = (float*)  carve((size_t)NLAYERS * HDIM * 4);
    float*   pool   = (float*)  carve((size_t)N_GRAPHS * HDIM * 4);  // 16384 B (256-mult)
    float*   cnt    = (float*)  carve((size_t)N_GRAPHS * 4);         // adjacent to pool

    const int nthreads = 256;
    const int e_blocks  = (N_EDGES + nthreads - 1) / nthreads;
    const int nc_blocks = (N_NODES * HDIM) / nthreads;

    // ---- CSR build (deg+cursor zeroed in one memset: adjacent carves) ----
    hipMemsetAsync(deg, 0, (size_t)N_NODES * 4 * 2, stream);
    count_deg_kernel<<<e_blocks, nthreads, 0, stream>>>(ei, deg);
    scan1_kernel<<<SCAN_NBLK, SCAN_B, 0, stream>>>(deg, rowptr, bsum);
    scan2_kernel<<<1, SCAN_B, 0, stream>>>(bsum, bscan);
    scan3_kernel<<<SCAN_NBLK, SCAN_B, 0, stream>>>(rowptr, bscan);
    fill_csr_kernel<<<e_blocks, nthreads, 0, stream>>>(ei, ea, rowptr, cursor, srcarr, ea8);

    // ---- projections / weight prep ----
    hipMemsetAsync(hbuf + (size_t)N_NODES * HDIM, 0,
                   (size_t)(M_PAD - N_NODES) * HDIM * 2, stream);  // zero pad rows
    nodeproj_kernel<<<nc_blocks, nthreads, 0, stream>>>(x, node_w, node_b, hbuf);
    fold_edge_kernel<<<NLAYERS * 6, HDIM, 0, stream>>>(edge_w, edge_b, We, Me_all, ce_all);
    convert_w_kernel<<<NLAYERS * 4 * HDIM, HDIM, 0, stream>>>(Wq, Wk, Wv, Wskip, Wtb);

    for (int i = 0; i < NLAYERS; ++i) {
        const float* Me = Me_all + i * 5 * HDIM;
        const float* ce = ce_all + i * HDIM;
        gemm_mfma<<<dim3(M_PAD / 128, 3), 256, 0, stream>>>(
            hbuf, Wtb + (size_t)i * 4 * HDIM * HDIM,
            bq + i * HDIM, bk + i * HDIM, bv + i * HDIM, bskip + i * HDIM,
            q2b, kv2b, ob);
        agg_kernel<<<N_NODES / 2, 128, 0, stream>>>(srcarr, rowptr, ea8, q2b, kv2b,
                                                    Me, ce, ob,
                                                    ln_g + i * HDIM, ln_b + i * HDIM, hbuf);
    }

    // pool+cnt zeroed in one memset (adjacent carves)
    hipMemsetAsync(pool, 0, (size_t)(N_GRAPHS * HDIM + N_GRAPHS) * 4, stream);
    pool_kernel<<<POOL_NBLK, HDIM, 0, stream>>>(hbuf, batch, pool, cnt);
    heads_kernel<<<N_GRAPHS, HDIM, 0, stream>>>(pool, cnt, dw1, db1, dw2, db2,
                                                tw1, tb1, tw2, tb2, out);
}

// Round 14
// 563.437 us; speedup vs baseline: 1.1019x; 1.1019x over previous
//
#include <hip/hip_runtime.h>
#include <hip/hip_fp16.h>
#include <math.h>

#define N_NODES 40000
#define N_EDGES 640000
#define N_GRAPHS 32
#define HDIM 128
#define NHEADS 4
#define CDIM 32
#define NLAYERS 4
#define ODIM 100
#define SCAN_B 256
#define SCAN_NBLK ((N_NODES + SCAN_B - 1) / SCAN_B)   // 157
#define M_PAD 40064                                   // 313 * 128
#define POOL_CHUNK 32
#define POOL_NBLK ((N_NODES + POOL_CHUNK - 1) / POOL_CHUNK)  // 1250
#define SCALE 0.17677669529663687f                    // 1/sqrt(32)

typedef __bf16 bf16_t;
typedef bf16_t bf16x8 __attribute__((ext_vector_type(8)));
typedef float f32x4 __attribute__((ext_vector_type(4)));
typedef _Float16 h2v __attribute__((ext_vector_type(2)));

#if defined(__has_builtin)
#if __has_builtin(__builtin_amdgcn_fdot2)
#define HAVE_FDOT2 1
#endif
#endif

// packed k/v pair for one (channel, channel+16) pair of one node
struct __align__(8) H2P { __half2 k; __half2 v; };

// ---------------------------------------------------------------------------
// h = x @ node_w + node_b   ([N,4]@[4,128]) -> bf16 feature buffer
__global__ void nodeproj_kernel(const float* __restrict__ x,
                                const float* __restrict__ w,
                                const float* __restrict__ b,
                                bf16_t* __restrict__ hb) {
    int idx = blockIdx.x * blockDim.x + threadIdx.x;
    if (idx >= N_NODES * HDIM) return;
    int n = idx >> 7, c = idx & 127;
    float s = b[c];
    s += x[n * 4 + 0] * w[0 * HDIM + c];
    s += x[n * 4 + 1] * w[1 * HDIM + c];
    s += x[n * 4 + 2] * w[2 * HDIM + c];
    s += x[n * 4 + 3] * w[3 * HDIM + c];
    hb[idx] = (bf16_t)s;
}

// ---------------------------------------------------------------------------
// Me[i] = edge_w @ We[i]  ([5,128]),  ce[i] = edge_b @ We[i]  ([128])
__global__ void fold_edge_kernel(const float* __restrict__ edge_w,
                                 const float* __restrict__ edge_b,
                                 const float* __restrict__ We,
                                 float* __restrict__ Me_all,
                                 float* __restrict__ ce_all) {
    int blk = blockIdx.x;
    int i = blk / 6, j = blk % 6;
    int c = threadIdx.x;
    const float* W = We + (size_t)i * HDIM * HDIM;
    float s = 0.0f;
    if (j < 5) {
        for (int k = 0; k < HDIM; ++k) s += edge_w[j * HDIM + k] * W[k * HDIM + c];
        Me_all[i * 5 * HDIM + j * HDIM + c] = s;
    } else {
        for (int k = 0; k < HDIM; ++k) s += edge_b[k] * W[k * HDIM + c];
        ce_all[i * HDIM + c] = s;
    }
}

// ---------------------------------------------------------------------------
// CSR build
__global__ void count_deg_kernel(const int* __restrict__ ei, int* __restrict__ deg) {
    int e = blockIdx.x * blockDim.x + threadIdx.x;
    if (e >= N_EDGES) return;
    atomicAdd(&deg[ei[N_EDGES + e]], 1);
}

__global__ void scan1_kernel(const int* __restrict__ deg,
                             int* __restrict__ rowptr, int* __restrict__ bsum) {
    __shared__ int sd[SCAN_B];
    int tid = threadIdx.x;
    int i = blockIdx.x * SCAN_B + tid;
    int v = (i < N_NODES) ? deg[i] : 0;
    sd[tid] = v;
    __syncthreads();
#pragma unroll
    for (int off = 1; off < SCAN_B; off <<= 1) {
        int tmp = (tid >= off) ? sd[tid - off] : 0;
        __syncthreads();
        sd[tid] += tmp;
        __syncthreads();
    }
    if (i < N_NODES) rowptr[i] = sd[tid] - v;
    if (tid == SCAN_B - 1) bsum[blockIdx.x] = sd[tid];
}

__global__ void scan2_kernel(const int* __restrict__ bsum, int* __restrict__ bscan) {
    __shared__ int sd[SCAN_B];
    int tid = threadIdx.x;
    int v = (tid < SCAN_NBLK) ? bsum[tid] : 0;
    sd[tid] = v;
    __syncthreads();
#pragma unroll
    for (int off = 1; off < SCAN_B; off <<= 1) {
        int tmp = (tid >= off) ? sd[tid - off] : 0;
        __syncthreads();
        sd[tid] += tmp;
        __syncthreads();
    }
    if (tid < SCAN_NBLK) bscan[tid] = sd[tid] - v;
}

__global__ void scan3_kernel(int* __restrict__ rowptr, const int* __restrict__ bscan) {
    int i = blockIdx.x * SCAN_B + threadIdx.x;
    if (i < N_NODES) rowptr[i] += bscan[blockIdx.x];
    if (i == 0) rowptr[N_NODES] = N_EDGES;
}

// scatter src + edge attrs (padded to 8 floats -> two float4 stores)
__global__ void fill_csr_kernel(const int* __restrict__ ei,
                                const float* __restrict__ ea,
                                const int* __restrict__ rowptr,
                                int* __restrict__ cursor,
                                int* __restrict__ srcarr,
                                float* __restrict__ ea8) {
    int e = blockIdx.x * blockDim.x + threadIdx.x;
    if (e >= N_EDGES) return;
    int src = ei[e], dst = ei[N_EDGES + e];
    int pos = atomicAdd(&cursor[dst], 1);
    int p = rowptr[dst] + pos;
    srcarr[p] = src;
    float4 lo = make_float4(ea[(size_t)e * 5 + 0], ea[(size_t)e * 5 + 1],
                            ea[(size_t)e * 5 + 2], ea[(size_t)e * 5 + 3]);
    float4 hi = make_float4(ea[(size_t)e * 5 + 4], 0.f, 0.f, 0.f);
    *(float4*)(ea8 + (size_t)p * 8)     = lo;
    *(float4*)(ea8 + (size_t)p * 8 + 4) = hi;
}

// ---------------------------------------------------------------------------
// Convert weights to bf16 [n][k]; Wk pre-scaled by 1/sqrt(C).
__global__ void convert_w_kernel(const float* __restrict__ Wq, const float* __restrict__ Wk,
                                 const float* __restrict__ Wv, const float* __restrict__ Ws,
                                 bf16_t* __restrict__ Wtb) {
    int b = blockIdx.x;
    int n = b & 127;
    int matli = b >> 7;
    int mat = matli & 3, li = matli >> 2;
    int kk = threadIdx.x;
    const float* W = (mat == 0 ? Wq : mat == 1 ? Wk : mat == 2 ? Wv : Ws) + (size_t)li * HDIM * HDIM;
    float val = W[kk * HDIM + n];
    if (mat == 1) val *= SCALE;
    Wtb[((size_t)(li * 4 + mat) * HDIM + n) * HDIM + kk] = (bf16_t)val;
}

// ---------------------------------------------------------------------------
// Fused projection GEMM (round-6 known-good). blockIdx.y: 0 -> q (packed
// half2 pairs), 1 -> k&v (H2P pairs, k pre-scaled), 2 -> skip (fp32).
// NOTE (r7 post-mortem): register-direct B from global regressed -- keep
// LDS-staged B.
__global__ __launch_bounds__(256) void gemm_mfma(
    const bf16_t* __restrict__ hb, const bf16_t* __restrict__ Wt,
    const float* __restrict__ bq, const float* __restrict__ bk,
    const float* __restrict__ bv, const float* __restrict__ bs,
    __half2* __restrict__ q2o, H2P* __restrict__ kv2o,
    float* __restrict__ so) {
    __shared__ bf16_t Ash[128 * 128];
    __shared__ bf16_t Bsh[128 * 128];
    int tid = threadIdx.x;
    int mt = blockIdx.y;
    int row0 = blockIdx.x * 128;
    int r = tid >> 4, g = tid & 15;

    {   // stage A and first B (q: slot0, kv: slot1=k, skip: slot3)
        const bf16_t* W0 = Wt + (size_t)(mt == 0 ? 0 : (mt == 1 ? 1 : 3)) * HDIM * HDIM;
#pragma unroll
        for (int p = 0; p < 8; ++p) {
            int rr = p * 16 + r;
            int sw = (g ^ (rr & 15)) << 3;
            *(bf16x8*)(Ash + rr * 128 + sw) = *(const bf16x8*)(hb + (size_t)(row0 + rr) * HDIM + g * 8);
            *(bf16x8*)(Bsh + rr * 128 + sw) = *(const bf16x8*)(W0 + (size_t)rr * HDIM + g * 8);
        }
    }
    __syncthreads();

    int lane = tid & 63, wave = tid >> 6;
    int wr = (wave >> 1) * 64, wc = (wave & 1) * 64;
    int lm = lane & 15, quad = lane >> 4;

    f32x4 acc[4][4];
#pragma unroll
    for (int i = 0; i < 4; ++i)
#pragma unroll
        for (int j = 0; j < 4; ++j) acc[i][j] = (f32x4){0.f, 0.f, 0.f, 0.f};

#pragma unroll
    for (int ks = 0; ks < 4; ++ks) {
        int gg = ks * 4 + quad;
        int sw = (gg ^ lm) << 3;
        bf16x8 af[4], bf[4];
#pragma unroll
        for (int t = 0; t < 4; ++t) {
            af[t] = *(const bf16x8*)(Ash + (wr + t * 16 + lm) * 128 + sw);
            bf[t] = *(const bf16x8*)(Bsh + (wc + t * 16 + lm) * 128 + sw);
        }
#pragma unroll
        for (int i = 0; i < 4; ++i)
#pragma unroll
            for (int j = 0; j < 4; ++j)
                acc[i][j] = __builtin_amdgcn_mfma_f32_16x16x32_bf16(af[i], bf[j], acc[i][j], 0, 0, 0);
    }

    int c0 = wc + lm;           // low channel of pair (j0,j1)
    int c2 = wc + lm + 32;      // low channel of pair (j2,j3)
    int pi0 = ((c0 >> 5) << 4) | lm;
    int pi1 = ((c2 >> 5) << 4) | lm;

    if (mt == 0) {
        float b0 = bq[c0], b1 = bq[c0 + 16], b2 = bq[c2], b3 = bq[c2 + 16];
#pragma unroll
        for (int i = 0; i < 4; ++i) {
            int rbase = row0 + wr + i * 16 + quad * 4;
#pragma unroll
            for (int rr2 = 0; rr2 < 4; ++rr2) {
                int row = rbase + rr2;
                if (row < N_NODES) {
                    q2o[(size_t)row * 64 + pi0] =
                        __floats2half2_rn(acc[i][0][rr2] + b0, acc[i][1][rr2] + b1);
                    q2o[(size_t)row * 64 + pi1] =
                        __floats2half2_rn(acc[i][2][rr2] + b2, acc[i][3][rr2] + b3);
                }
            }
        }
    } else if (mt == 1) {
        // second pass: v (slot 2)
        f32x4 acc2[4][4];
#pragma unroll
        for (int i = 0; i < 4; ++i)
#pragma unroll
            for (int j = 0; j < 4; ++j) acc2[i][j] = (f32x4){0.f, 0.f, 0.f, 0.f};
        __syncthreads();
        {
            const bf16_t* W1 = Wt + (size_t)2 * HDIM * HDIM;
#pragma unroll
            for (int p = 0; p < 8; ++p) {
                int rr = p * 16 + r;
                int sw = (g ^ (rr & 15)) << 3;
                *(bf16x8*)(Bsh + rr * 128 + sw) = *(const bf16x8*)(W1 + (size_t)rr * HDIM + g * 8);
            }
        }
        __syncthreads();
#pragma unroll
        for (int ks = 0; ks < 4; ++ks) {
            int gg = ks * 4 + quad;
            int sw = (gg ^ lm) << 3;
            bf16x8 af[4], bf[4];
#pragma unroll
            for (int t = 0; t < 4; ++t) {
                af[t] = *(const bf16x8*)(Ash + (wr + t * 16 + lm) * 128 + sw);
                bf[t] = *(const bf16x8*)(Bsh + (wc + t * 16 + lm) * 128 + sw);
            }
#pragma unroll
            for (int i = 0; i < 4; ++i)
#pragma unroll
                for (int j = 0; j < 4; ++j)
                    acc2[i][j] = __builtin_amdgcn_mfma_f32_16x16x32_bf16(af[i], bf[j], acc2[i][j], 0, 0, 0);
        }
        float kb0 = bk[c0] * SCALE, kb1 = bk[c0 + 16] * SCALE;
        float kb2 = bk[c2] * SCALE, kb3 = bk[c2 + 16] * SCALE;
        float vb0 = bv[c0], vb1 = bv[c0 + 16], vb2 = bv[c2], vb3 = bv[c2 + 16];
#pragma unroll
        for (int i = 0; i < 4; ++i) {
            int rbase = row0 + wr + i * 16 + quad * 4;
#pragma unroll
            for (int rr2 = 0; rr2 < 4; ++rr2) {
                int row = rbase + rr2;
                if (row < N_NODES) {
                    H2P h0, h1;
                    h0.k = __floats2half2_rn(acc[i][0][rr2] + kb0, acc[i][1][rr2] + kb1);
                    h0.v = __floats2half2_rn(acc2[i][0][rr2] + vb0, acc2[i][1][rr2] + vb1);
                    h1.k = __floats2half2_rn(acc[i][2][rr2] + kb2, acc[i][3][rr2] + kb3);
                    h1.v = __floats2half2_rn(acc2[i][2][rr2] + vb2, acc2[i][3][rr2] + vb3);
                    kv2o[(size_t)row * 64 + pi0] = h0;
                    kv2o[(size_t)row * 64 + pi1] = h1;
                }
            }
        }
    } else {
#pragma unroll
        for (int i = 0; i < 4; ++i) {
            int rbase = row0 + wr + i * 16 + quad * 4;
#pragma unroll
            for (int j = 0; j < 4; ++j) {
                int col = wc + j * 16 + lm;
                float bcol = bs[col];
#pragma unroll
                for (int rr2 = 0; rr2 < 4; ++rr2) {
                    int row = rbase + rr2;
                    if (row < N_NODES) so[(size_t)row * HDIM + col] = acc[i][j][rr2] + bcol;
                }
            }
        }
    }
}

// ---------------------------------------------------------------------------
// Fused per-dst-node attention + skip + LayerNorm + ReLU.
// ONE WAVE per node; lane t owns channel pair (clo, clo+16). No online max
// (r9). r10 structure: two-deep register pipeline with simple rotation
// (REVERTED from r12's ping-pong: VGPR 48->56 dropped occupancy 45->37%,
// +14us -- register pressure beats instruction count in this gather loop).
// Kept from r12: v_dot2_f32_f16 k-dot (no extra live values, free).
// Block = 128 = 2 nodes.
__global__ __launch_bounds__(128) void agg_kernel(
    const int* __restrict__ srcarr, const int* __restrict__ rowptr,
    const float* __restrict__ ea8,
    const __half2* __restrict__ q2,
    const H2P* __restrict__ kv2,
    const float* __restrict__ Me, const float* __restrict__ ce,
    const float* __restrict__ skip,
    const float* __restrict__ lg, const float* __restrict__ lb,
    bf16_t* __restrict__ hbout) {
    int t = threadIdx.x & 63;
    int n = blockIdx.x * 2 + (threadIdx.x >> 6);
    int cc = t & 15;
    int clo = ((t >> 4) << 5) | cc;
    int chi = clo + 16;

    __half2 qh = q2[(size_t)n * 64 + t];
    float2 qf = __half22float2(qh);
    float cwlo = ce[clo], cwhi = ce[chi];
    float mlo[5], mhi[5];
#pragma unroll
    for (int j = 0; j < 5; ++j) { mlo[j] = Me[j * HDIM + clo]; mhi[j] = Me[j * HDIM + chi]; }

    // per-node per-head preamble: lane cc==j gets SCALE * (q_h . Mvec_j_h)
    float myq = 0.0f;
#pragma unroll
    for (int j = 0; j < 6; ++j) {
        float a = (j < 5) ? mlo[j] : cwlo;
        float b = (j < 5) ? mhi[j] : cwhi;
        float p = (qf.x * a + qf.y * b) * SCALE;
        p += __shfl_xor(p, 8, 16);
        p += __shfl_xor(p, 4, 16);
        p += __shfl_xor(p, 2, 16);
        p += __shfl_xor(p, 1, 16);
        if (cc == j) myq = p;
    }

    int beg = rowptr[n], end = rowptr[n + 1];
    float l[4], o0[4], o1[4], ab[4];
#pragma unroll
    for (int s = 0; s < 4; ++s) { l[s] = 0.f; o0[s] = 0.f; o1[s] = 0.f; ab[s] = 0.f; }

    if (beg < end) {   // wave-uniform; deg-0 nodes skip all loads
        int e1 = end - 1;
        int srcB[4];
        float avA[4], avB[4];
        H2P kvA[4];
        // pipeline fill: indices for G0 and G1, kv for G0
        {
            int srcA[4];
#pragma unroll
            for (int s = 0; s < 4; ++s) {
                int ca = beg + s;       ca = (ca < e1) ? ca : e1;
                int cb = beg + 4 + s;   cb = (cb < e1) ? cb : e1;
                srcA[s] = srcarr[ca];
                srcB[s] = srcarr[cb];
                avA[s] = (cc < 5) ? ea8[(size_t)ca * 8 + cc] : 1.0f;
                avB[s] = (cc < 5) ? ea8[(size_t)cb * 8 + cc] : 1.0f;
            }
#pragma unroll
            for (int s = 0; s < 4; ++s) kvA[s] = kv2[(size_t)srcA[s] * 64 + t];
        }

        for (int base = beg; base < end; base += 4) {
            // issue next-group kv loads (indices ready from 2 iters back)
            H2P kvB[4];
#pragma unroll
            for (int s = 0; s < 4; ++s) kvB[s] = kv2[(size_t)srcB[s] * 64 + t];
            // issue indices/attrs for group G+2
            int srcC[4]; float avC[4];
#pragma unroll
            for (int s = 0; s < 4; ++s) {
                int cidx = base + 8 + s; cidx = (cidx < e1) ? cidx : e1;
                srcC[s] = srcarr[cidx];
                avC[s] = (cc < 5) ? ea8[(size_t)cidx * 8 + cc] : 1.0f;
            }
            // process current group (kvA loaded last iteration)
            float p4[4], vx[4], vy[4];
#pragma unroll
            for (int s = 0; s < 4; ++s) {
                float2 vf = __half22float2(kvA[s].v);
                vx[s] = vf.x; vy[s] = vf.y;
                float pa = myq * avA[s];
#if defined(HAVE_FDOT2)
                p4[s] = __builtin_amdgcn_fdot2(__builtin_bit_cast(h2v, qh),
                                               __builtin_bit_cast(h2v, kvA[s].k), pa, false);
#else
                float2 kf = __half22float2(kvA[s].k);
                p4[s] = fmaf(qf.x, kf.x, fmaf(qf.y, kf.y, pa));
#endif
            }
#pragma unroll
            for (int st = 8; st >= 1; st >>= 1) {
#pragma unroll
                for (int s = 0; s < 4; ++s) p4[s] += __shfl_xor(p4[s], st, 16);
            }
#pragma unroll
            for (int s = 0; s < 4; ++s) {
                float pe = (base + s < end) ? __expf(p4[s]) : 0.0f;  // uniform select
                o0[s] = fmaf(pe, vx[s], o0[s]);
                o1[s] = fmaf(pe, vy[s], o1[s]);
                l[s] += pe;
                ab[s] = fmaf(pe, avA[s], ab[s]);
            }
            // rotate pipeline
#pragma unroll
            for (int s = 0; s < 4; ++s) {
                kvA[s] = kvB[s];
                avA[s] = avB[s];
                srcB[s] = srcC[s];
                avB[s] = avC[s];
            }
        }
    }
    // merge 4 states: plain sums
    float lt  = (l[0] + l[1]) + (l[2] + l[3]);
    float o0t = (o0[0] + o0[1]) + (o0[2] + o0[3]);
    float o1t = (o1[0] + o1[1]) + (o1[2] + o1[3]);
    float abt = (ab[0] + ab[1]) + (ab[2] + ab[3]);

    // msg = (o + l*ce + sum_j Me_j * ab_j) / (l + 1e-16)
    float nlo = fmaf(lt, cwlo, o0t);
    float nhi = fmaf(lt, cwhi, o1t);
#pragma unroll
    for (int j = 0; j < 5; ++j) {
        float abj = __shfl(abt, (t & 48) + j, 64);
        nlo = fmaf(mlo[j], abj, nlo);
        nhi = fmaf(mhi[j], abj, nhi);
    }
    float inv = 1.0f / (lt + 1e-16f);
    float vlo = skip[(size_t)n * HDIM + clo] + nlo * inv;
    float vhi = skip[(size_t)n * HDIM + chi] + nhi * inv;

    // LayerNorm over 128 channels -- single-wave butterfly
    float s = vlo + vhi;
#pragma unroll
    for (int mask = 32; mask >= 1; mask >>= 1) s += __shfl_xor(s, mask, 64);
    float mu = s * (1.0f / HDIM);
    float dlo = vlo - mu, dhi = vhi - mu;
    float s2 = dlo * dlo + dhi * dhi;
#pragma unroll
    for (int mask = 32; mask >= 1; mask >>= 1) s2 += __shfl_xor(s2, mask, 64);
    float rstd = rsqrtf(s2 * (1.0f / HDIM) + 1e-5f);
    float ylo = fmaxf(dlo * rstd * lg[clo] + lb[clo], 0.0f);
    float yhi = fmaxf(dhi * rstd * lg[chi] + lb[chi], 0.0f);
    hbout[(size_t)n * HDIM + clo] = (bf16_t)ylo;
    hbout[(size_t)n * HDIM + chi] = (bf16_t)yhi;
}

// ---------------------------------------------------------------------------
// Chunked mean-pool. r11: POOL_CHUNK 256->32 (157->1250 blocks).
__global__ __launch_bounds__(128) void pool_kernel(const bf16_t* __restrict__ h,
                                                   const int* __restrict__ batch,
                                                   float* __restrict__ pool,
                                                   float* __restrict__ cnt) {
    int t = threadIdx.x;
    int n0 = blockIdx.x * POOL_CHUNK;
    int n1 = n0 + POOL_CHUNK;
    if (n1 > N_NODES) n1 = N_NODES;
    int gcur = batch[n0];
    int cstart = n0;
    float acc = 0.0f;
    for (int n = n0; n < n1; ++n) {
        int g = batch[n];
        if (g != gcur) {
            atomicAdd(&pool[gcur * HDIM + t], acc);
            if (t == 0) atomicAdd(&cnt[gcur], (float)(n - cstart));
            acc = 0.0f;
            gcur = g;
            cstart = n;
        }
        acc += (float)h[(size_t)n * HDIM + t];
    }
    atomicAdd(&pool[gcur * HDIM + t], acc);
    if (t == 0) atomicAdd(&cnt[gcur], (float)(n1 - cstart));
}

// ---------------------------------------------------------------------------
__global__ void heads_kernel(const float* __restrict__ pool,
                             const float* __restrict__ cnt,
                             const float* __restrict__ dw1, const float* __restrict__ db1,
                             const float* __restrict__ dw2, const float* __restrict__ db2,
                             const float* __restrict__ tw1, const float* __restrict__ tb1,
                             const float* __restrict__ tw2, const float* __restrict__ tb2,
                             float* __restrict__ outp) {
    int g = blockIdx.x, t = threadIdx.x;
    __shared__ float hg[HDIM];
    __shared__ float hid[64];
    float c = fmaxf(cnt[g], 1.0f);
    hg[t] = pool[g * HDIM + t] / c;
    __syncthreads();
    if (t < 64) {
        float s = db1[t];
        for (int i = 0; i < HDIM; ++i) s += hg[i] * dw1[i * 64 + t];
        hid[t] = fmaxf(s, 0.0f);
    }
    __syncthreads();
    if (t < ODIM) {
        float s = db2[t];
        for (int j = 0; j < 64; ++j) s += hid[j] * dw2[j * ODIM + t];
        outp[g * ODIM + t] = s;
    }
    __syncthreads();
    if (t < 64) {
        float s = tb1[t];
        for (int i = 0; i < HDIM; ++i) s += hg[i] * tw1[i * 64 + t];
        hid[t] = fmaxf(s, 0.0f);
    }
    __syncthreads();
    if (t < ODIM) {
        float s = tb2[t];
        for (int j = 0; j < 64; ++j) s += hid[j] * tw2[j * ODIM + t];
        outp[N_GRAPHS * ODIM + g * ODIM + t] = s;
    }
}

// ---------------------------------------------------------------------------
extern "C" void kernel_launch(void* const* d_in, const int* in_sizes, int n_in,
                              void* d_out, int out_size, void* d_ws, size_t ws_size,
                              hipStream_t stream) {
    const float* x        = (const float*)d_in[0];
    const float* ea       = (const float*)d_in[1];
    const float* node_w   = (const float*)d_in[2];
    const float* node_b   = (const float*)d_in[3];
    const float* edge_w   = (const float*)d_in[4];
    const float* edge_b   = (const float*)d_in[5];
    const float* Wq       = (const float*)d_in[6];
    const float* bq       = (const float*)d_in[7];
    const float* Wk       = (const float*)d_in[8];
    const float* bk       = (const float*)d_in[9];
    const float* Wv       = (const float*)d_in[10];
    const float* bv       = (const float*)d_in[11];
    const float* We       = (const float*)d_in[12];
    const float* Wskip    = (const float*)d_in[13];
    const float* bskip    = (const float*)d_in[14];
    const float* ln_g     = (const float*)d_in[15];
    const float* ln_b     = (const float*)d_in[16];
    const float* dw1      = (const float*)d_in[17];
    const float* db1      = (const float*)d_in[18];
    const float* dw2      = (const float*)d_in[19];
    const float* db2      = (const float*)d_in[20];
    const float* tw1      = (const float*)d_in[21];
    const float* tb1      = (const float*)d_in[22];
    const float* tw2      = (const float*)d_in[23];
    const float* tb2      = (const float*)d_in[24];
    const int*   ei       = (const int*)d_in[25];
    const int*   batch    = (const int*)d_in[26];
    float* out = (float*)d_out;
    (void)in_sizes; (void)n_in; (void)out_size; (void)ws_size;

    // ---- workspace carve (256B aligned) ----
    char* wsb = (char*)d_ws;
    size_t off = 0;
    auto carve = [&](size_t bytes) -> void* {
        void* p = wsb + off;
        off += (bytes + 255) & ~(size_t)255;
        return p;
    };
    bf16_t*  hbuf   = (bf16_t*) carve((size_t)M_PAD * HDIM * 2);
    __half2* q2b    = (__half2*)carve((size_t)N_NODES * 64 * 4);
    H2P*     kv2b   = (H2P*)    carve((size_t)N_NODES * 64 * 8);
    float*   ob     = (float*)  carve((size_t)N_NODES * HDIM * 4);   // skip buffer
    bf16_t*  Wtb    = (bf16_t*) carve((size_t)NLAYERS * 4 * HDIM * HDIM * 2);
    int*     srcarr = (int*)    carve((size_t)N_EDGES * 4);
    float*   ea8    = (float*)  carve((size_t)N_EDGES * 8 * 4);
    int*     deg    = (int*)    carve((size_t)N_NODES * 4);          // 160000 B (256-mult)
    int*     cursor = (int*)    carve((size_t)N_NODES * 4);          // adjacent to deg
    int*     rowptr = (int*)    carve((size_t)(N_NODES + 1) * 4);
    int*     bsum   = (int*)    carve((size_t)SCAN_NBLK * 4);
    int*     bscan  = (int*)    carve((size_t)SCAN_NBLK * 4);
    float*   Me_all = (float*)  carve((size_t)NLAYERS * 5 * HDIM * 4);
    float*   ce_all = (float*)  carve((size_t)NLAYERS * HDIM * 4);
    float*   pool   = (float*)  carve((size_t)N_GRAPHS * HDIM * 4);  // 16384 B (256-mult)
    float*   cnt    = (float*)  carve((size_t)N_GRAPHS * 4);         // adjacent to pool

    const int nthreads = 256;
    const int e_blocks  = (N_EDGES + nthreads - 1) / nthreads;
    const int nc_blocks = (N_NODES * HDIM) / nthreads;

    // ---- CSR build (deg+cursor zeroed in one memset: adjacent carves) ----
    hipMemsetAsync(deg, 0, (size_t)N_NODES * 4 * 2, stream);
    count_deg_kernel<<<e_blocks, nthreads, 0, stream>>>(ei, deg);
    scan1_kernel<<<SCAN_NBLK, SCAN_B, 0, stream>>>(deg, rowptr, bsum);
    scan2_kernel<<<1, SCAN_B, 0, stream>>>(bsum, bscan);
    scan3_kernel<<<SCAN_NBLK, SCAN_B, 0, stream>>>(rowptr, bscan);
    fill_csr_kernel<<<e_blocks, nthreads, 0, stream>>>(ei, ea, rowptr, cursor, srcarr, ea8);

    // ---- projections / weight prep ----
    hipMemsetAsync(hbuf + (size_t)N_NODES * HDIM, 0,
                   (size_t)(M_PAD - N_NODES) * HDIM * 2, stream);  // zero pad rows
    nodeproj_kernel<<<nc_blocks, nthreads, 0, stream>>>(x, node_w, node_b, hbuf);
    fold_edge_kernel<<<NLAYERS * 6, HDIM, 0, stream>>>(edge_w, edge_b, We, Me_all, ce_all);
    convert_w_kernel<<<NLAYERS * 4 * HDIM, HDIM, 0, stream>>>(Wq, Wk, Wv, Wskip, Wtb);

    for (int i = 0; i < NLAYERS; ++i) {
        const float* Me = Me_all + i * 5 * HDIM;
        const float* ce = ce_all + i * HDIM;
        gemm_mfma<<<dim3(M_PAD / 128, 3), 256, 0, stream>>>(
            hbuf, Wtb + (size_t)i * 4 * HDIM * HDIM,
            bq + i * HDIM, bk + i * HDIM, bv + i * HDIM, bskip + i * HDIM,
            q2b, kv2b, ob);
        agg_kernel<<<N_NODES / 2, 128, 0, stream>>>(srcarr, rowptr, ea8, q2b, kv2b,
                                                    Me, ce, ob,
                                                    ln_g + i * HDIM, ln_b + i * HDIM, hbuf);
    }

    // pool+cnt zeroed in one memset (adjacent carves)
    hipMemsetAsync(pool, 0, (size_t)(N_GRAPHS * HDIM + N_GRAPHS) * 4, stream);
    pool_kernel<<<POOL_NBLK, HDIM, 0, stream>>>(hbuf, batch, pool, cnt);
    heads_kernel<<<N_GRAPHS, HDIM, 0, stream>>>(pool, cnt, dw1, db1, dw2, db2,
                                                tw1, tb1, tw2, tb2, out);
}

// Round 15
// 545.637 us; speedup vs baseline: 1.1378x; 1.0326x over previous
//
#include <hip/hip_runtime.h>
#include <hip/hip_fp16.h>
#include <math.h>

#define N_NODES 40000
#define N_EDGES 640000
#define N_GRAPHS 32
#define HDIM 128
#define NHEADS 4
#define CDIM 32
#define NLAYERS 4
#define ODIM 100
#define SCAN_B 256
#define SCAN_NBLK ((N_NODES + SCAN_B - 1) / SCAN_B)   // 157
#define M_PAD 40064                                   // 313 * 128
#define POOL_CHUNK 32
#define POOL_NBLK ((N_NODES + POOL_CHUNK - 1) / POOL_CHUNK)  // 1250
#define SCALE 0.17677669529663687f                    // 1/sqrt(32)

typedef __bf16 bf16_t;
typedef bf16_t bf16x8 __attribute__((ext_vector_type(8)));
typedef float f32x4 __attribute__((ext_vector_type(4)));
typedef _Float16 h2v __attribute__((ext_vector_type(2)));

#if defined(__has_builtin)
#if __has_builtin(__builtin_amdgcn_fdot2)
#define HAVE_FDOT2 1
#endif
#endif

// packed k/v pair for one (channel, channel+16) pair of one node
struct __align__(8) H2P { __half2 k; __half2 v; };

// ---------------------------------------------------------------------------
// h = x @ node_w + node_b   ([N,4]@[4,128]) -> bf16 feature buffer
__global__ void nodeproj_kernel(const float* __restrict__ x,
                                const float* __restrict__ w,
                                const float* __restrict__ b,
                                bf16_t* __restrict__ hb) {
    int idx = blockIdx.x * blockDim.x + threadIdx.x;
    if (idx >= N_NODES * HDIM) return;
    int n = idx >> 7, c = idx & 127;
    float s = b[c];
    s += x[n * 4 + 0] * w[0 * HDIM + c];
    s += x[n * 4 + 1] * w[1 * HDIM + c];
    s += x[n * 4 + 2] * w[2 * HDIM + c];
    s += x[n * 4 + 3] * w[3 * HDIM + c];
    hb[idx] = (bf16_t)s;
}

// ---------------------------------------------------------------------------
// Me[i] = edge_w @ We[i]  ([5,128]),  ce[i] = edge_b @ We[i]  ([128])
__global__ void fold_edge_kernel(const float* __restrict__ edge_w,
                                 const float* __restrict__ edge_b,
                                 const float* __restrict__ We,
                                 float* __restrict__ Me_all,
                                 float* __restrict__ ce_all) {
    int blk = blockIdx.x;
    int i = blk / 6, j = blk % 6;
    int c = threadIdx.x;
    const float* W = We + (size_t)i * HDIM * HDIM;
    float s = 0.0f;
    if (j < 5) {
        for (int k = 0; k < HDIM; ++k) s += edge_w[j * HDIM + k] * W[k * HDIM + c];
        Me_all[i * 5 * HDIM + j * HDIM + c] = s;
    } else {
        for (int k = 0; k < HDIM; ++k) s += edge_b[k] * W[k * HDIM + c];
        ce_all[i * HDIM + c] = s;
    }
}

// ---------------------------------------------------------------------------
// CSR build
__global__ void count_deg_kernel(const int* __restrict__ ei, int* __restrict__ deg) {
    int e = blockIdx.x * blockDim.x + threadIdx.x;
    if (e >= N_EDGES) return;
    atomicAdd(&deg[ei[N_EDGES + e]], 1);
}

__global__ void scan1_kernel(const int* __restrict__ deg,
                             int* __restrict__ rowptr, int* __restrict__ bsum) {
    __shared__ int sd[SCAN_B];
    int tid = threadIdx.x;
    int i = blockIdx.x * SCAN_B + tid;
    int v = (i < N_NODES) ? deg[i] : 0;
    sd[tid] = v;
    __syncthreads();
#pragma unroll
    for (int off = 1; off < SCAN_B; off <<= 1) {
        int tmp = (tid >= off) ? sd[tid - off] : 0;
        __syncthreads();
        sd[tid] += tmp;
        __syncthreads();
    }
    if (i < N_NODES) rowptr[i] = sd[tid] - v;
    if (tid == SCAN_B - 1) bsum[blockIdx.x] = sd[tid];
}

__global__ void scan2_kernel(const int* __restrict__ bsum, int* __restrict__ bscan) {
    __shared__ int sd[SCAN_B];
    int tid = threadIdx.x;
    int v = (tid < SCAN_NBLK) ? bsum[tid] : 0;
    sd[tid] = v;
    __syncthreads();
#pragma unroll
    for (int off = 1; off < SCAN_B; off <<= 1) {
        int tmp = (tid >= off) ? sd[tid - off] : 0;
        __syncthreads();
        sd[tid] += tmp;
        __syncthreads();
    }
    if (tid < SCAN_NBLK) bscan[tid] = sd[tid] - v;
}

__global__ void scan3_kernel(int* __restrict__ rowptr, const int* __restrict__ bscan) {
    int i = blockIdx.x * SCAN_B + threadIdx.x;
    if (i < N_NODES) rowptr[i] += bscan[blockIdx.x];
    if (i == 0) rowptr[N_NODES] = N_EDGES;
}

// scatter src + edge attrs (padded to 8 floats -> two float4 stores)
__global__ void fill_csr_kernel(const int* __restrict__ ei,
                                const float* __restrict__ ea,
                                const int* __restrict__ rowptr,
                                int* __restrict__ cursor,
                                int* __restrict__ srcarr,
                                float* __restrict__ ea8) {
    int e = blockIdx.x * blockDim.x + threadIdx.x;
    if (e >= N_EDGES) return;
    int src = ei[e], dst = ei[N_EDGES + e];
    int pos = atomicAdd(&cursor[dst], 1);
    int p = rowptr[dst] + pos;
    srcarr[p] = src;
    float4 lo = make_float4(ea[(size_t)e * 5 + 0], ea[(size_t)e * 5 + 1],
                            ea[(size_t)e * 5 + 2], ea[(size_t)e * 5 + 3]);
    float4 hi = make_float4(ea[(size_t)e * 5 + 4], 0.f, 0.f, 0.f);
    *(float4*)(ea8 + (size_t)p * 8)     = lo;
    *(float4*)(ea8 + (size_t)p * 8 + 4) = hi;
}

// ---------------------------------------------------------------------------
// Convert weights to bf16 [n][k]; Wk pre-scaled by 1/sqrt(C).
__global__ void convert_w_kernel(const float* __restrict__ Wq, const float* __restrict__ Wk,
                                 const float* __restrict__ Wv, const float* __restrict__ Ws,
                                 bf16_t* __restrict__ Wtb) {
    int b = blockIdx.x;
    int n = b & 127;
    int matli = b >> 7;
    int mat = matli & 3, li = matli >> 2;
    int kk = threadIdx.x;
    const float* W = (mat == 0 ? Wq : mat == 1 ? Wk : mat == 2 ? Wv : Ws) + (size_t)li * HDIM * HDIM;
    float val = W[kk * HDIM + n];
    if (mat == 1) val *= SCALE;
    Wtb[((size_t)(li * 4 + mat) * HDIM + n) * HDIM + kk] = (bf16_t)val;
}

// ---------------------------------------------------------------------------
// Fused projection GEMM. r14: 512-thread blocks (8 waves, 2x4 wave grid,
// each wave a 64x32 strip, acc[4][2]) on the same 64 KB LDS -> 2 blocks/CU
// = 16 waves/CU (was 8). Same data flow as the r6 known-good (LDS-staged B;
// r7 showed register-direct B regresses). blockIdx.y: 0 -> q (packed half2
// pairs), 1 -> k&v (H2P, k pre-scaled), 2 -> skip (fp32).
// Pair layout: wave's 32-col strip = one pair group, pi = ((wave&3)<<4)|lm.
__global__ __launch_bounds__(512) void gemm_mfma(
    const bf16_t* __restrict__ hb, const bf16_t* __restrict__ Wt,
    const float* __restrict__ bq, const float* __restrict__ bk,
    const float* __restrict__ bv, const float* __restrict__ bs,
    __half2* __restrict__ q2o, H2P* __restrict__ kv2o,
    float* __restrict__ so) {
    __shared__ bf16_t Ash[128 * 128];
    __shared__ bf16_t Bsh[128 * 128];
    int tid = threadIdx.x;
    int mt = blockIdx.y;
    int row0 = blockIdx.x * 128;

    {   // stage A and first B (q: slot0, kv: slot1=k, skip: slot3)
        const bf16_t* W0 = Wt + (size_t)(mt == 0 ? 0 : (mt == 1 ? 1 : 3)) * HDIM * HDIM;
#pragma unroll
        for (int p = 0; p < 4; ++p) {
            int i = tid + p * 512;
            int rr = i >> 4, g = i & 15;
            int sw = (g ^ (rr & 15)) << 3;
            *(bf16x8*)(Ash + rr * 128 + sw) = *(const bf16x8*)(hb + (size_t)(row0 + rr) * HDIM + g * 8);
            *(bf16x8*)(Bsh + rr * 128 + sw) = *(const bf16x8*)(W0 + (size_t)rr * HDIM + g * 8);
        }
    }
    __syncthreads();

    int lane = tid & 63, wave = tid >> 6;           // wave 0..7
    int wr = (wave >> 2) * 64, wc = (wave & 3) * 32;
    int lm = lane & 15, quad = lane >> 4;

    f32x4 acc[4][2];
#pragma unroll
    for (int i = 0; i < 4; ++i)
#pragma unroll
        for (int j = 0; j < 2; ++j) acc[i][j] = (f32x4){0.f, 0.f, 0.f, 0.f};

#pragma unroll
    for (int ks = 0; ks < 4; ++ks) {
        int gg = ks * 4 + quad;
        int sw = (gg ^ lm) << 3;
        bf16x8 af[4], bf[2];
#pragma unroll
        for (int t = 0; t < 4; ++t)
            af[t] = *(const bf16x8*)(Ash + (wr + t * 16 + lm) * 128 + sw);
#pragma unroll
        for (int j = 0; j < 2; ++j)
            bf[j] = *(const bf16x8*)(Bsh + (wc + j * 16 + lm) * 128 + sw);
#pragma unroll
        for (int i = 0; i < 4; ++i)
#pragma unroll
            for (int j = 0; j < 2; ++j)
                acc[i][j] = __builtin_amdgcn_mfma_f32_16x16x32_bf16(af[i], bf[j], acc[i][j], 0, 0, 0);
    }

    int c0 = wc + lm;                    // low channel of the wave's pair
    int pi = ((wave & 3) << 4) | lm;     // pair index in agg layout

    if (mt == 0) {
        float b0 = bq[c0], b1 = bq[c0 + 16];
#pragma unroll
        for (int i = 0; i < 4; ++i) {
            int rbase = row0 + wr + i * 16 + quad * 4;
#pragma unroll
            for (int r = 0; r < 4; ++r) {
                int row = rbase + r;
                if (row < N_NODES)
                    q2o[(size_t)row * 64 + pi] =
                        __floats2half2_rn(acc[i][0][r] + b0, acc[i][1][r] + b1);
            }
        }
    } else if (mt == 1) {
        // second pass: v (slot 2)
        f32x4 acc2[4][2];
#pragma unroll
        for (int i = 0; i < 4; ++i)
#pragma unroll
            for (int j = 0; j < 2; ++j) acc2[i][j] = (f32x4){0.f, 0.f, 0.f, 0.f};
        __syncthreads();
        {
            const bf16_t* W1 = Wt + (size_t)2 * HDIM * HDIM;
#pragma unroll
            for (int p = 0; p < 4; ++p) {
                int i = tid + p * 512;
                int rr = i >> 4, g = i & 15;
                int sw = (g ^ (rr & 15)) << 3;
                *(bf16x8*)(Bsh + rr * 128 + sw) = *(const bf16x8*)(W1 + (size_t)rr * HDIM + g * 8);
            }
        }
        __syncthreads();
#pragma unroll
        for (int ks = 0; ks < 4; ++ks) {
            int gg = ks * 4 + quad;
            int sw = (gg ^ lm) << 3;
            bf16x8 af[4], bf[2];
#pragma unroll
            for (int t = 0; t < 4; ++t)
                af[t] = *(const bf16x8*)(Ash + (wr + t * 16 + lm) * 128 + sw);
#pragma unroll
            for (int j = 0; j < 2; ++j)
                bf[j] = *(const bf16x8*)(Bsh + (wc + j * 16 + lm) * 128 + sw);
#pragma unroll
            for (int i = 0; i < 4; ++i)
#pragma unroll
                for (int j = 0; j < 2; ++j)
                    acc2[i][j] = __builtin_amdgcn_mfma_f32_16x16x32_bf16(af[i], bf[j], acc2[i][j], 0, 0, 0);
        }
        float kb0 = bk[c0] * SCALE, kb1 = bk[c0 + 16] * SCALE;
        float vb0 = bv[c0], vb1 = bv[c0 + 16];
#pragma unroll
        for (int i = 0; i < 4; ++i) {
            int rbase = row0 + wr + i * 16 + quad * 4;
#pragma unroll
            for (int r = 0; r < 4; ++r) {
                int row = rbase + r;
                if (row < N_NODES) {
                    H2P h;
                    h.k = __floats2half2_rn(acc[i][0][r] + kb0, acc[i][1][r] + kb1);
                    h.v = __floats2half2_rn(acc2[i][0][r] + vb0, acc2[i][1][r] + vb1);
                    kv2o[(size_t)row * 64 + pi] = h;
                }
            }
        }
    } else {
        float b0 = bs[c0], b1 = bs[c0 + 16];
#pragma unroll
        for (int i = 0; i < 4; ++i) {
            int rbase = row0 + wr + i * 16 + quad * 4;
#pragma unroll
            for (int r = 0; r < 4; ++r) {
                int row = rbase + r;
                if (row < N_NODES) {
                    so[(size_t)row * HDIM + c0]      = acc[i][0][r] + b0;
                    so[(size_t)row * HDIM + c0 + 16] = acc[i][1][r] + b1;
                }
            }
        }
    }
}

// ---------------------------------------------------------------------------
// Fused per-dst-node attention + skip + LayerNorm + ReLU (r13 known-good).
// ONE WAVE per node; lane t owns channel pair (clo, clo+16). No online max
// (r9). r10 two-deep pipeline w/ simple rotation (r12 ping-pong regressed:
// VGPR pressure beats instruction count). fdot2 k-dot kept (free).
__global__ __launch_bounds__(128) void agg_kernel(
    const int* __restrict__ srcarr, const int* __restrict__ rowptr,
    const float* __restrict__ ea8,
    const __half2* __restrict__ q2,
    const H2P* __restrict__ kv2,
    const float* __restrict__ Me, const float* __restrict__ ce,
    const float* __restrict__ skip,
    const float* __restrict__ lg, const float* __restrict__ lb,
    bf16_t* __restrict__ hbout) {
    int t = threadIdx.x & 63;
    int n = blockIdx.x * 2 + (threadIdx.x >> 6);
    int cc = t & 15;
    int clo = ((t >> 4) << 5) | cc;
    int chi = clo + 16;

    __half2 qh = q2[(size_t)n * 64 + t];
    float2 qf = __half22float2(qh);
    float cwlo = ce[clo], cwhi = ce[chi];
    float mlo[5], mhi[5];
#pragma unroll
    for (int j = 0; j < 5; ++j) { mlo[j] = Me[j * HDIM + clo]; mhi[j] = Me[j * HDIM + chi]; }

    // per-node per-head preamble: lane cc==j gets SCALE * (q_h . Mvec_j_h)
    float myq = 0.0f;
#pragma unroll
    for (int j = 0; j < 6; ++j) {
        float a = (j < 5) ? mlo[j] : cwlo;
        float b = (j < 5) ? mhi[j] : cwhi;
        float p = (qf.x * a + qf.y * b) * SCALE;
        p += __shfl_xor(p, 8, 16);
        p += __shfl_xor(p, 4, 16);
        p += __shfl_xor(p, 2, 16);
        p += __shfl_xor(p, 1, 16);
        if (cc == j) myq = p;
    }

    int beg = rowptr[n], end = rowptr[n + 1];
    float l[4], o0[4], o1[4], ab[4];
#pragma unroll
    for (int s = 0; s < 4; ++s) { l[s] = 0.f; o0[s] = 0.f; o1[s] = 0.f; ab[s] = 0.f; }

    if (beg < end) {   // wave-uniform; deg-0 nodes skip all loads
        int e1 = end - 1;
        int srcB[4];
        float avA[4], avB[4];
        H2P kvA[4];
        // pipeline fill: indices for G0 and G1, kv for G0
        {
            int srcA[4];
#pragma unroll
            for (int s = 0; s < 4; ++s) {
                int ca = beg + s;       ca = (ca < e1) ? ca : e1;
                int cb = beg + 4 + s;   cb = (cb < e1) ? cb : e1;
                srcA[s] = srcarr[ca];
                srcB[s] = srcarr[cb];
                avA[s] = (cc < 5) ? ea8[(size_t)ca * 8 + cc] : 1.0f;
                avB[s] = (cc < 5) ? ea8[(size_t)cb * 8 + cc] : 1.0f;
            }
#pragma unroll
            for (int s = 0; s < 4; ++s) kvA[s] = kv2[(size_t)srcA[s] * 64 + t];
        }

        for (int base = beg; base < end; base += 4) {
            // issue next-group kv loads (indices ready from 2 iters back)
            H2P kvB[4];
#pragma unroll
            for (int s = 0; s < 4; ++s) kvB[s] = kv2[(size_t)srcB[s] * 64 + t];
            // issue indices/attrs for group G+2
            int srcC[4]; float avC[4];
#pragma unroll
            for (int s = 0; s < 4; ++s) {
                int cidx = base + 8 + s; cidx = (cidx < e1) ? cidx : e1;
                srcC[s] = srcarr[cidx];
                avC[s] = (cc < 5) ? ea8[(size_t)cidx * 8 + cc] : 1.0f;
            }
            // process current group (kvA loaded last iteration)
            float p4[4], vx[4], vy[4];
#pragma unroll
            for (int s = 0; s < 4; ++s) {
                float2 vf = __half22float2(kvA[s].v);
                vx[s] = vf.x; vy[s] = vf.y;
                float pa = myq * avA[s];
#if defined(HAVE_FDOT2)
                p4[s] = __builtin_amdgcn_fdot2(__builtin_bit_cast(h2v, qh),
                                               __builtin_bit_cast(h2v, kvA[s].k), pa, false);
#else
                float2 kf = __half22float2(kvA[s].k);
                p4[s] = fmaf(qf.x, kf.x, fmaf(qf.y, kf.y, pa));
#endif
            }
#pragma unroll
            for (int st = 8; st >= 1; st >>= 1) {
#pragma unroll
                for (int s = 0; s < 4; ++s) p4[s] += __shfl_xor(p4[s], st, 16);
            }
#pragma unroll
            for (int s = 0; s < 4; ++s) {
                float pe = (base + s < end) ? __expf(p4[s]) : 0.0f;  // uniform select
                o0[s] = fmaf(pe, vx[s], o0[s]);
                o1[s] = fmaf(pe, vy[s], o1[s]);
                l[s] += pe;
                ab[s] = fmaf(pe, avA[s], ab[s]);
            }
            // rotate pipeline
#pragma unroll
            for (int s = 0; s < 4; ++s) {
                kvA[s] = kvB[s];
                avA[s] = avB[s];
                srcB[s] = srcC[s];
                avB[s] = avC[s];
            }
        }
    }
    // merge 4 states: plain sums
    float lt  = (l[0] + l[1]) + (l[2] + l[3]);
    float o0t = (o0[0] + o0[1]) + (o0[2] + o0[3]);
    float o1t = (o1[0] + o1[1]) + (o1[2] + o1[3]);
    float abt = (ab[0] + ab[1]) + (ab[2] + ab[3]);

    // msg = (o + l*ce + sum_j Me_j * ab_j) / (l + 1e-16)
    float nlo = fmaf(lt, cwlo, o0t);
    float nhi = fmaf(lt, cwhi, o1t);
#pragma unroll
    for (int j = 0; j < 5; ++j) {
        float abj = __shfl(abt, (t & 48) + j, 64);
        nlo = fmaf(mlo[j], abj, nlo);
        nhi = fmaf(mhi[j], abj, nhi);
    }
    float inv = 1.0f / (lt + 1e-16f);
    float vlo = skip[(size_t)n * HDIM + clo] + nlo * inv;
    float vhi = skip[(size_t)n * HDIM + chi] + nhi * inv;

    // LayerNorm over 128 channels -- single-wave butterfly
    float s = vlo + vhi;
#pragma unroll
    for (int mask = 32; mask >= 1; mask >>= 1) s += __shfl_xor(s, mask, 64);
    float mu = s * (1.0f / HDIM);
    float dlo = vlo - mu, dhi = vhi - mu;
    float s2 = dlo * dlo + dhi * dhi;
#pragma unroll
    for (int mask = 32; mask >= 1; mask >>= 1) s2 += __shfl_xor(s2, mask, 64);
    float rstd = rsqrtf(s2 * (1.0f / HDIM) + 1e-5f);
    float ylo = fmaxf(dlo * rstd * lg[clo] + lb[clo], 0.0f);
    float yhi = fmaxf(dhi * rstd * lg[chi] + lb[chi], 0.0f);
    hbout[(size_t)n * HDIM + clo] = (bf16_t)ylo;
    hbout[(size_t)n * HDIM + chi] = (bf16_t)yhi;
}

// ---------------------------------------------------------------------------
// Chunked mean-pool. r11: POOL_CHUNK 256->32 (157->1250 blocks).
__global__ __launch_bounds__(128) void pool_kernel(const bf16_t* __restrict__ h,
                                                   const int* __restrict__ batch,
                                                   float* __restrict__ pool,
                                                   float* __restrict__ cnt) {
    int t = threadIdx.x;
    int n0 = blockIdx.x * POOL_CHUNK;
    int n1 = n0 + POOL_CHUNK;
    if (n1 > N_NODES) n1 = N_NODES;
    int gcur = batch[n0];
    int cstart = n0;
    float acc = 0.0f;
    for (int n = n0; n < n1; ++n) {
        int g = batch[n];
        if (g != gcur) {
            atomicAdd(&pool[gcur * HDIM + t], acc);
            if (t == 0) atomicAdd(&cnt[gcur], (float)(n - cstart));
            acc = 0.0f;
            gcur = g;
            cstart = n;
        }
        acc += (float)h[(size_t)n * HDIM + t];
    }
    atomicAdd(&pool[gcur * HDIM + t], acc);
    if (t == 0) atomicAdd(&cnt[gcur], (float)(n1 - cstart));
}

// ---------------------------------------------------------------------------
__global__ void heads_kernel(const float* __restrict__ pool,
                             const float* __restrict__ cnt,
                             const float* __restrict__ dw1, const float* __restrict__ db1,
                             const float* __restrict__ dw2, const float* __restrict__ db2,
                             const float* __restrict__ tw1, const float* __restrict__ tb1,
                             const float* __restrict__ tw2, const float* __restrict__ tb2,
                             float* __restrict__ outp) {
    int g = blockIdx.x, t = threadIdx.x;
    __shared__ float hg[HDIM];
    __shared__ float hid[64];
    float c = fmaxf(cnt[g], 1.0f);
    hg[t] = pool[g * HDIM + t] / c;
    __syncthreads();
    if (t < 64) {
        float s = db1[t];
        for (int i = 0; i < HDIM; ++i) s += hg[i] * dw1[i * 64 + t];
        hid[t] = fmaxf(s, 0.0f);
    }
    __syncthreads();
    if (t < ODIM) {
        float s = db2[t];
        for (int j = 0; j < 64; ++j) s += hid[j] * dw2[j * ODIM + t];
        outp[g * ODIM + t] = s;
    }
    __syncthreads();
    if (t < 64) {
        float s = tb1[t];
        for (int i = 0; i < HDIM; ++i) s += hg[i] * tw1[i * 64 + t];
        hid[t] = fmaxf(s, 0.0f);
    }
    __syncthreads();
    if (t < ODIM) {
        float s = tb2[t];
        for (int j = 0; j < 64; ++j) s += hid[j] * tw2[j * ODIM + t];
        outp[N_GRAPHS * ODIM + g * ODIM + t] = s;
    }
}

// ---------------------------------------------------------------------------
extern "C" void kernel_launch(void* const* d_in, const int* in_sizes, int n_in,
                              void* d_out, int out_size, void* d_ws, size_t ws_size,
                              hipStream_t stream) {
    const float* x        = (const float*)d_in[0];
    const float* ea       = (const float*)d_in[1];
    const float* node_w   = (const float*)d_in[2];
    const float* node_b   = (const float*)d_in[3];
    const float* edge_w   = (const float*)d_in[4];
    const float* edge_b   = (const float*)d_in[5];
    const float* Wq       = (const float*)d_in[6];
    const float* bq       = (const float*)d_in[7];
    const float* Wk       = (const float*)d_in[8];
    const float* bk       = (const float*)d_in[9];
    const float* Wv       = (const float*)d_in[10];
    const float* bv       = (const float*)d_in[11];
    const float* We       = (const float*)d_in[12];
    const float* Wskip    = (const float*)d_in[13];
    const float* bskip    = (const float*)d_in[14];
    const float* ln_g     = (const float*)d_in[15];
    const float* ln_b     = (const float*)d_in[16];
    const float* dw1      = (const float*)d_in[17];
    const float* db1      = (const float*)d_in[18];
    const float* dw2      = (const float*)d_in[19];
    const float* db2      = (const float*)d_in[20];
    const float* tw1      = (const float*)d_in[21];
    const float* tb1      = (const float*)d_in[22];
    const float* tw2      = (const float*)d_in[23];
    const float* tb2      = (const float*)d_in[24];
    const int*   ei       = (const int*)d_in[25];
    const int*   batch    = (const int*)d_in[26];
    float* out = (float*)d_out;
    (void)in_sizes; (void)n_in; (void)out_size; (void)ws_size;

    // ---- workspace carve (256B aligned) ----
    char* wsb = (char*)d_ws;
    size_t off = 0;
    auto carve = [&](size_t bytes) -> void* {
        void* p = wsb + off;
        off += (bytes + 255) & ~(size_t)255;
        return p;
    };
    bf16_t*  hbuf   = (bf16_t*) carve((size_t)M_PAD * HDIM * 2);
    __half2* q2b    = (__half2*)carve((size_t)N_NODES * 64 * 4);
    H2P*     kv2b   = (H2P*)    carve((size_t)N_NODES * 64 * 8);
    float*   ob     = (float*)  carve((size_t)N_NODES * HDIM * 4);   // skip buffer
    bf16_t*  Wtb    = (bf16_t*) carve((size_t)NLAYERS * 4 * HDIM * HDIM * 2);
    int*     srcarr = (int*)    carve((size_t)N_EDGES * 4);
    float*   ea8    = (float*)  carve((size_t)N_EDGES * 8 * 4);
    int*     deg    = (int*)    carve((size_t)N_NODES * 4);          // 160000 B (256-mult)
    int*     cursor = (int*)    carve((size_t)N_NODES * 4);          // adjacent to deg
    int*     rowptr = (int*)    carve((size_t)(N_NODES + 1) * 4);
    int*     bsum   = (int*)    carve((size_t)SCAN_NBLK * 4);
    int*     bscan  = (int*)    carve((size_t)SCAN_NBLK * 4);
    float*   Me_all = (float*)  carve((size_t)NLAYERS * 5 * HDIM * 4);
    float*   ce_all = (float*)  carve((size_t)NLAYERS * HDIM * 4);
    float*   pool   = (float*)  carve((size_t)N_GRAPHS * HDIM * 4);  // 16384 B (256-mult)
    float*   cnt    = (float*)  carve((size_t)N_GRAPHS * 4);         // adjacent to pool

    const int nthreads = 256;
    const int e_blocks  = (N_EDGES + nthreads - 1) / nthreads;
    const int nc_blocks = (N_NODES * HDIM) / nthreads;

    // ---- CSR build (deg+cursor zeroed in one memset: adjacent carves) ----
    hipMemsetAsync(deg, 0, (size_t)N_NODES * 4 * 2, stream);
    count_deg_kernel<<<e_blocks, nthreads, 0, stream>>>(ei, deg);
    scan1_kernel<<<SCAN_NBLK, SCAN_B, 0, stream>>>(deg, rowptr, bsum);
    scan2_kernel<<<1, SCAN_B, 0, stream>>>(bsum, bscan);
    scan3_kernel<<<SCAN_NBLK, SCAN_B, 0, stream>>>(rowptr, bscan);
    fill_csr_kernel<<<e_blocks, nthreads, 0, stream>>>(ei, ea, rowptr, cursor, srcarr, ea8);

    // ---- projections / weight prep ----
    hipMemsetAsync(hbuf + (size_t)N_NODES * HDIM, 0,
                   (size_t)(M_PAD - N_NODES) * HDIM * 2, stream);  // zero pad rows
    nodeproj_kernel<<<nc_blocks, nthreads, 0, stream>>>(x, node_w, node_b, hbuf);
    fold_edge_kernel<<<NLAYERS * 6, HDIM, 0, stream>>>(edge_w, edge_b, We, Me_all, ce_all);
    convert_w_kernel<<<NLAYERS * 4 * HDIM, HDIM, 0, stream>>>(Wq, Wk, Wv, Wskip, Wtb);

    for (int i = 0; i < NLAYERS; ++i) {
        const float* Me = Me_all + i * 5 * HDIM;
        const float* ce = ce_all + i * HDIM;
        gemm_mfma<<<dim3(M_PAD / 128, 3), 512, 0, stream>>>(
            hbuf, Wtb + (size_t)i * 4 * HDIM * HDIM,
            bq + i * HDIM, bk + i * HDIM, bv + i * HDIM, bskip + i * HDIM,
            q2b, kv2b, ob);
        agg_kernel<<<N_NODES / 2, 128, 0, stream>>>(srcarr, rowptr, ea8, q2b, kv2b,
                                                    Me, ce, ob,
                                                    ln_g + i * HDIM, ln_b + i * HDIM, hbuf);
    }

    // pool+cnt zeroed in one memset (adjacent carves)
    hipMemsetAsync(pool, 0, (size_t)(N_GRAPHS * HDIM + N_GRAPHS) * 4, stream);
    pool_kernel<<<POOL_NBLK, HDIM, 0, stream>>>(hbuf, batch, pool, cnt);
    heads_kernel<<<N_GRAPHS, HDIM, 0, stream>>>(pool, cnt, dw1, db1, dw2, db2,
                                                tw1, tb1, tw2, tb2, out);
}